// Round 5
// baseline (212.130 us; speedup 1.0000x reference)
//
#include <hip/hip_runtime.h>

// Problem constants (from reference setup_inputs)
#define N_TRAIN 4096
#define N_UNL   32768
#define C_DIM   1000
#define G_GRP   512
#define K_MEM   64

#define CE_BLOCKS (N_TRAIN / 16)          // 256 blocks, 16 rows each
#define NBLK      (G_GRP + CE_BLOCKS)     // 768 blocks total

#define CHUNKS  8
#define CCOLS   128                       // fp32 columns per chunk
#define PITCH_B 272                       // LDS row pitch BYTES (128 bf16 + 16 pad; 4-bank stride)
#define ROWS    80                        // 64 members + centroid row 64 + 15 unread rows

typedef short        short8 __attribute__((ext_vector_type(8)));   // 8 bf16 (4 VGPRs)
typedef float        f32x4  __attribute__((ext_vector_type(4)));   // MFMA accumulator
typedef unsigned int u32x2  __attribute__((ext_vector_type(2)));   // 8 B store

// pack two f32 -> two bf16 (round-half-up via +0x8000; inputs ~N(0,1), no overflow risk)
__device__ __forceinline__ unsigned int pack_bf(float a, float b) {
    unsigned int ua = __float_as_uint(a) + 0x8000u;
    unsigned int ub = __float_as_uint(b) + 0x8000u;
    return (ua >> 16) | (ub & 0xffff0000u);
}

// ---------------------------------------------------------------------------
// Fused kernel. Blocks 0..511: group path — depth-2 register-prefetch gather,
// double-buffered bf16 LDS (1 barrier/chunk), MFMA gram, align+robust partial
// -> atomicAdd. Blocks 512..767: CE path (16 rows each -> atomicAdd).
// ---------------------------------------------------------------------------
__global__ __launch_bounds__(256) void fused_kernel(const float* __restrict__ train,
                                                    const int*   __restrict__ targets,
                                                    const float* __restrict__ unl,
                                                    const int*   __restrict__ cids,
                                                    const int*   __restrict__ mids,
                                                    float* __restrict__ out) {
    __shared__ __align__(16) unsigned short bf[2][ROWS * (PITCH_B / 2)];  // 2 x 21760 B
    __shared__ int   ids_sh[K_MEM];
    __shared__ float sq_sh[K_MEM];
    __shared__ float red_sh[256];
    __shared__ float sqc_sh;

    const int tid  = threadIdx.x;
    const int w    = tid >> 6;
    const int lane = tid & 63;

    if (blockIdx.x >= G_GRP) {
        // ------------------------- CE path -------------------------
        const int blk = (int)blockIdx.x - G_GRP;
        float ce = 0.f;
        for (int r4 = 0; r4 < 4; ++r4) {
            const int row = blk * 16 + w * 4 + r4;
            const float* rp = train + (long)row * C_DIM;
            float x[16];
#pragma unroll
            for (int i = 0; i < 16; ++i) {
                int c = lane + i * 64;
                x[i] = (c < C_DIM) ? rp[c] : -1e30f;
            }
            float m = x[0];
#pragma unroll
            for (int i = 1; i < 16; ++i) m = fmaxf(m, x[i]);
#pragma unroll
            for (int off = 32; off > 0; off >>= 1) m = fmaxf(m, __shfl_xor(m, off, 64));
            float s = 0.f;
#pragma unroll
            for (int i = 0; i < 16; ++i) s += __expf(x[i] - m);
#pragma unroll
            for (int off = 32; off > 0; off >>= 1) s += __shfl_xor(s, off, 64);
            if (lane == 0) {
                int t = targets[row];
                ce += -(rp[t] - m - __logf(s));
            }
        }
        if (lane == 0) red_sh[w] = ce;
        __syncthreads();
        if (tid == 0)
            atomicAdd(out, (red_sh[0] + red_sh[1] + red_sh[2] + red_sh[3]) *
                           (1.0f / (float)N_TRAIN));
        return;
    }

    // ------------------------- group path -------------------------
    const int g    = blockIdx.x;
    const int quad = lane >> 4;
    const int c16  = lane & 15;

    if (tid < K_MEM) ids_sh[tid] = mids[g * K_MEM + tid];
    __syncthreads();

    // staging map: thread (rgrp,l32) owns rows rgrp+8i, fp32 cols [l32*4, l32*4+4)
    const int rgrp = tid >> 5;          // 0..7
    const int l32  = tid & 31;
    const int cid  = cids[g];

    const float* srcb[8];
#pragma unroll
    for (int i = 0; i < 8; ++i)
        srcb[i] = unl + (long)ids_sh[rgrp + 8 * i] * C_DIM + l32 * 4;
    const float* csrc = train + (long)cid * C_DIM + l32 * 4;    // used by tid<32 only

    f32x4 acc[4], accC, accD;
#pragma unroll
    for (int t = 0; t < 4; ++t) acc[t] = (f32x4){0.f, 0.f, 0.f, 0.f};
    accC = (f32x4){0.f, 0.f, 0.f, 0.f};
    accD = (f32x4){0.f, 0.f, 0.f, 0.f};

    const float4 z4 = make_float4(0.f, 0.f, 0.f, 0.f);

    float4 mreg[2][8];
    float4 creg[2];

    // prefetch chunks 0 and 1 (depth-2)
#pragma unroll
    for (int p = 0; p < 2; ++p) {
        const long off = (long)p * CCOLS;
#pragma unroll
        for (int i = 0; i < 8; ++i) mreg[p][i] = *(const float4*)(srcb[i] + off);
        if (tid < 32) creg[p] = *(const float4*)(csrc + off);
    }

    for (int ch = 0; ch < CHUNKS; ++ch) {
        const int buf = ch & 1;
        // ---- commit prefetched regs -> bf16 LDS buf (ds_write_b64) ----
        // (safe vs laggard MFMA readers of the OTHER buffer)
#pragma unroll
        for (int i = 0; i < 8; ++i) {
            u32x2 h = {pack_bf(mreg[buf][i].x, mreg[buf][i].y),
                       pack_bf(mreg[buf][i].z, mreg[buf][i].w)};
            *(u32x2*)((char*)bf[buf] + (rgrp + 8 * i) * PITCH_B + l32 * 8) = h;
        }
        if (tid < 32) {
            u32x2 h = {pack_bf(creg[buf].x, creg[buf].y),
                       pack_bf(creg[buf].z, creg[buf].w)};
            *(u32x2*)((char*)bf[buf] + 64 * PITCH_B + tid * 8) = h;
        }
        __syncthreads();   // buf committed; prev buf's readers all done

        // ---- issue chunk ch+2 loads (overlap with MFMA below; reuse reg set) ----
        if (ch + 2 < CHUNKS) {
            const int col = (ch + 2) * CCOLS + l32 * 4;
            const bool v = (col < C_DIM);        // C_DIM%4==0 -> per-float4 check exact
            const long off = (long)(ch + 2) * CCOLS;
#pragma unroll
            for (int i = 0; i < 8; ++i)
                mreg[buf][i] = v ? *(const float4*)(srcb[i] + off) : z4;
            if (tid < 32) creg[buf] = v ? *(const float4*)(csrc + off) : z4;
        }

        // ---- MFMA: tiles (w,0..3), centroid x (w), and ||c||^2 on wave 0 ----
#pragma unroll
        for (int s = 0; s < 4; ++s) {
            const int kbb = s * 64 + quad * 16;     // byte offset within 256 B row chunk
            const char* base = (const char*)bf[buf];
            short8 b0 = *(const short8*)(base + (0 * 16 + c16) * PITCH_B + kbb);
            short8 b1 = *(const short8*)(base + (1 * 16 + c16) * PITCH_B + kbb);
            short8 b2 = *(const short8*)(base + (2 * 16 + c16) * PITCH_B + kbb);
            short8 b3 = *(const short8*)(base + (3 * 16 + c16) * PITCH_B + kbb);
            short8 aM = *(const short8*)(base + (w * 16 + c16) * PITCH_B + kbb);
            short8 aC = *(const short8*)(base + (64 + c16) * PITCH_B + kbb);
            acc[0] = __builtin_amdgcn_mfma_f32_16x16x32_bf16(aM, b0, acc[0], 0, 0, 0);
            acc[1] = __builtin_amdgcn_mfma_f32_16x16x32_bf16(aM, b1, acc[1], 0, 0, 0);
            acc[2] = __builtin_amdgcn_mfma_f32_16x16x32_bf16(aM, b2, acc[2], 0, 0, 0);
            acc[3] = __builtin_amdgcn_mfma_f32_16x16x32_bf16(aM, b3, acc[3], 0, 0, 0);
            accC   = __builtin_amdgcn_mfma_f32_16x16x32_bf16(aC, aM, accC, 0, 0, 0);
            if (w == 0)
                accD = __builtin_amdgcn_mfma_f32_16x16x32_bf16(aC, aC, accD, 0, 0, 0);
        }
        // no second barrier: next iteration writes the other buffer
    }

    // ---- gram diagonal -> sq_sh (tile (w,w): i = w*16+quad*4+r, j = w*16+c16) ----
#pragma unroll
    for (int t = 0; t < 4; ++t) {
        if (t == w) {
#pragma unroll
            for (int r = 0; r < 4; ++r)
                if (c16 == quad * 4 + r) sq_sh[w * 16 + c16] = acc[t][r];
        }
    }
    if (tid == 0) sqc_sh = accD[0];        // ||c||^2
    __syncthreads();

    float local = 0.f;
    // align: centroid-tile row 64 -> quad==0, reg 0; col j = w*16+c16
    if (quad == 0) {
        const int j = w * 16 + c16;
        const float d2 = sqc_sh + sq_sh[j] - 2.f * accC[0];
        if (d2 > 0.f) local += sqrtf(d2) * (1.0f / (float)N_UNL);        // LAMBDA_1 = 1
    }
    // robust: upper triangle of member gram
#pragma unroll
    for (int t = 0; t < 4; ++t) {
#pragma unroll
        for (int r = 0; r < 4; ++r) {
            const int i = w * 16 + quad * 4 + r;
            const int j = t * 16 + c16;
            if (j > i) {
                const float d2 = sq_sh[i] + sq_sh[j] - 2.f * acc[t][r];
                if (d2 > 0.f)
                    local += sqrtf(d2) * (0.5f / ((float)K_MEM * (float)N_UNL)); // L2=0.5
            }
        }
    }

    red_sh[tid] = local;
    __syncthreads();
#pragma unroll
    for (int s = 128; s > 0; s >>= 1) {
        if (tid < s) red_sh[tid] += red_sh[tid + s];
        __syncthreads();
    }
    if (tid == 0) atomicAdd(out, red_sh[0]);
}

// ---------------------------------------------------------------------------
extern "C" void kernel_launch(void* const* d_in, const int* in_sizes, int n_in,
                              void* d_out, int out_size, void* d_ws, size_t ws_size,
                              hipStream_t stream) {
    (void)in_sizes; (void)n_in; (void)d_ws; (void)ws_size;
    const float* train_logits  = (const float*)d_in[0];
    const int*   train_targets = (const int*)d_in[1];
    const float* unl           = (const float*)d_in[2];
    const int*   centroid_ids  = (const int*)d_in[3];
    const int*   member_ids    = (const int*)d_in[4];
    float* out = (float*)d_out;

    hipMemsetAsync(out, 0, (size_t)out_size * sizeof(float), stream);
    fused_kernel<<<NBLK, 256, 0, stream>>>(train_logits, train_targets, unl,
                                           centroid_ids, member_ids, out);
}